// Round 1
// baseline (1227.268 us; speedup 1.0000x reference)
//
#include <hip/hip_runtime.h>
#include <stdint.h>

// GAT (2-layer) + sigmoid classifier for MI355X.
// N=50000 nodes, E=800000 edges (+N self loops), 128 features, 4 heads x 32.
//
// Pipeline per call:
//   CSR build (hist -> scan -> scatter)        [graph fixed per call, reused by both layers]
//   layer l: GEMM+att dots -> edge max -> edge exp/sum -> per-node gather aggregation
//   classifier: dot(128) + sigmoid
//
// All f32 (reference is f32; no fp32 MFMA on CDNA4 -> vector ALU GEMM).

#define NN 50000
#define NE 800000
#define ET 850000  // NE + NN self-loops

// order-preserving float<->uint encoding for atomicMax on floats
__device__ __forceinline__ unsigned encf(float f){
  unsigned u = __float_as_uint(f);
  return (u & 0x80000000u) ? ~u : (u | 0x80000000u);
}
__device__ __forceinline__ float decf(unsigned u){
  unsigned v = (u & 0x80000000u) ? (u & 0x7fffffffu) : ~u;
  return __uint_as_float(v);
}
__device__ __forceinline__ float lrelu(float v){ return v > 0.f ? v : 0.2f*v; }

// ---- CSR build -------------------------------------------------------------

__global__ void k_hist(const int* __restrict__ ei, int* __restrict__ count){
  int e = blockIdx.x*256 + threadIdx.x;
  if (e >= ET) return;
  int dst = (e < NE) ? ei[NE + e] : (e - NE);
  atomicAdd(&count[dst], 1);
}

__global__ void k_scan1(const int* __restrict__ count, int* __restrict__ incl,
                        int* __restrict__ btot, int n){
  __shared__ int sm[1024];
  int i = blockIdx.x*1024 + threadIdx.x;
  int v = (i < n) ? count[i] : 0;
  sm[threadIdx.x] = v;
  __syncthreads();
  for (int off = 1; off < 1024; off <<= 1){
    int t = (threadIdx.x >= off) ? sm[threadIdx.x - off] : 0;
    __syncthreads();
    sm[threadIdx.x] += t;
    __syncthreads();
  }
  if (i < n) incl[i] = sm[threadIdx.x];
  if (threadIdx.x == 1023) btot[blockIdx.x] = sm[1023];
}

__global__ void k_scan2(int* btot, int nb){  // single-wave exclusive scan of block totals
  int t = threadIdx.x;
  int orig = (t < nb) ? btot[t] : 0;
  int v = orig;
  for (int off = 1; off < 64; off <<= 1){
    int u = __shfl_up(v, off);
    if (t >= off) v += u;
  }
  if (t < nb) btot[t] = v - orig;
}

__global__ void k_scan3(int* __restrict__ offs_incl, const int* __restrict__ count,
                        const int* __restrict__ btot, int* __restrict__ cursor, int n){
  int i = blockIdx.x*1024 + threadIdx.x;
  if (i >= n) return;
  int excl = offs_incl[i] - count[i] + btot[blockIdx.x];
  offs_incl[i] = excl;   // in-place: incl -> excl
  cursor[i] = excl;
}

__global__ void k_scatter(const int* __restrict__ ei, int* __restrict__ cursor,
                          int2* __restrict__ csr){
  int e = blockIdx.x*256 + threadIdx.x;
  if (e >= ET) return;
  int src, dst;
  if (e < NE){ src = ei[e]; dst = ei[NE + e]; } else { src = dst = e - NE; }
  int pos = atomicAdd(&cursor[dst], 1);
  csr[pos] = make_int2(src, e);
}

// ---- GEMM (X @ W) fused with attention dot products ------------------------
// block = 256 threads = 2 rows x 128 cols; W staged fully in LDS (64 KB).
// bias_in (may be null) is added to the INPUT row (layer-2 input = agg1 + b1).

__launch_bounds__(256, 2)
__global__ void k_gemm_att(const float* __restrict__ X, const float* __restrict__ bias_in,
                           const float* __restrict__ W,
                           const float* __restrict__ att_s, const float* __restrict__ att_d,
                           float* __restrict__ Hout, float* __restrict__ As, float* __restrict__ Ad)
{
  __shared__ float Ws[128*128];
  __shared__ float xs[2][128];
  int tid = threadIdx.x;
  for (int i = tid*4; i < 128*128; i += 256*4){
    *(float4*)&Ws[i] = *(const float4*)&W[i];
  }
  int j  = tid & 127;   // output feature (= input feature during staging)
  int rh = tid >> 7;    // which of the 2 rows this half-block owns
  float atts = att_s[j];
  float attd = att_d[j];
  float bj = bias_in ? bias_in[j] : 0.f;
  __syncthreads();

  for (int p = blockIdx.x; p < NN/2; p += gridDim.x){
    int row = p*2 + rh;
    xs[rh][j] = X[(size_t)row*128 + j] + bj;
    __syncthreads();
    float a0=0.f, a1=0.f, a2=0.f, a3=0.f;
    #pragma unroll
    for (int k = 0; k < 128; k += 4){
      a0 += xs[rh][k+0]*Ws[(k+0)*128 + j];
      a1 += xs[rh][k+1]*Ws[(k+1)*128 + j];
      a2 += xs[rh][k+2]*Ws[(k+2)*128 + j];
      a3 += xs[rh][k+3]*Ws[(k+3)*128 + j];
    }
    float acc = (a0+a1)+(a2+a3);
    Hout[(size_t)row*128 + j] = acc;
    // attention dots: reduce over d (32 consecutive lanes = one head)
    float ps = acc*atts, pd = acc*attd;
    #pragma unroll
    for (int off = 16; off >= 1; off >>= 1){
      ps += __shfl_xor(ps, off);
      pd += __shfl_xor(pd, off);
    }
    if ((j & 31) == 0){
      As[row*4 + (j>>5)] = ps;
      Ad[row*4 + (j>>5)] = pd;
    }
    __syncthreads();
  }
}

// ---- edge passes: e = lrelu(a_src+a_dst); segment max; exp; segment sum ----

__global__ void k_edge1(const int* __restrict__ ei, const float* __restrict__ As,
                        const float* __restrict__ Ad, float* __restrict__ pbuf,
                        unsigned* __restrict__ menc){
  int e = blockIdx.x*256 + threadIdx.x;
  if (e >= ET) return;
  int src, dst;
  if (e < NE){ src = ei[e]; dst = ei[NE + e]; } else { src = dst = e - NE; }
  float4 a = *(const float4*)&As[src*4];
  float4 b = *(const float4*)&Ad[dst*4];
  float4 v;
  v.x = lrelu(a.x+b.x); v.y = lrelu(a.y+b.y);
  v.z = lrelu(a.z+b.z); v.w = lrelu(a.w+b.w);
  *(float4*)&pbuf[(size_t)e*4] = v;
  atomicMax(&menc[dst*4+0], encf(v.x));
  atomicMax(&menc[dst*4+1], encf(v.y));
  atomicMax(&menc[dst*4+2], encf(v.z));
  atomicMax(&menc[dst*4+3], encf(v.w));
}

__global__ void k_edge2(const int* __restrict__ ei, float* __restrict__ pbuf,
                        const unsigned* __restrict__ menc, float* __restrict__ S){
  int e = blockIdx.x*256 + threadIdx.x;
  if (e >= ET) return;
  int dst = (e < NE) ? ei[NE + e] : (e - NE);
  float4 v = *(float4*)&pbuf[(size_t)e*4];
  uint4 m = *(const uint4*)&menc[dst*4];
  float4 pv;
  pv.x = __expf(v.x - decf(m.x));
  pv.y = __expf(v.y - decf(m.y));
  pv.z = __expf(v.z - decf(m.z));
  pv.w = __expf(v.w - decf(m.w));
  *(float4*)&pbuf[(size_t)e*4] = pv;
  atomicAdd(&S[dst*4+0], pv.x);
  atomicAdd(&S[dst*4+1], pv.y);
  atomicAdd(&S[dst*4+2], pv.z);
  atomicAdd(&S[dst*4+3], pv.w);
}

// ---- aggregation: out[dst] = sum_e alpha[e] * h[src(e)] (CSR gather, no atomics)
// one wave per node; lane owns features {lane, lane+64} -> heads {lane>>5, 2+(lane>>5)}

__launch_bounds__(256)
__global__ void k_aggr(const int2* __restrict__ csr, const int* __restrict__ offs,
                       const int* __restrict__ count, const float* __restrict__ Hin,
                       const float* __restrict__ pbuf, const float* __restrict__ S,
                       float* __restrict__ Out)
{
  int node = blockIdx.x*4 + (threadIdx.x >> 6);
  if (node >= NN) return;
  int lane = threadIdx.x & 63;
  int start = offs[node];
  int cnt = count[node];
  float4 sv = *(const float4*)&S[node*4];
  bool hi = (lane & 32) != 0;
  float sa = 1.f / ((hi ? sv.y : sv.x) + 1e-16f);
  float sb = 1.f / ((hi ? sv.w : sv.z) + 1e-16f);
  float acc0 = 0.f, acc1 = 0.f;
  for (int i = 0; i < cnt; i++){
    int2 se = csr[start + i];                       // broadcast
    float4 pv = *(const float4*)&pbuf[(size_t)se.y*4];  // broadcast
    float pa = hi ? pv.y : pv.x;
    float pb = hi ? pv.w : pv.z;
    const float* hrow = &Hin[(size_t)se.x*128];     // 2x 256B coalesced
    acc0 += (pa*sa) * hrow[lane];
    acc1 += (pb*sb) * hrow[64 + lane];
  }
  Out[(size_t)node*128 + lane]      = acc0;
  Out[(size_t)node*128 + 64 + lane] = acc1;
}

// ---- classifier: sigmoid((h+b2) @ Wc + bc) ---------------------------------

__global__ void k_cls(const float* __restrict__ Hf, const float* __restrict__ b2,
                      const float* __restrict__ Wc, const float* __restrict__ bc,
                      float* __restrict__ y)
{
  int node = blockIdx.x*4 + (threadIdx.x >> 6);
  if (node >= NN) return;
  int lane = threadIdx.x & 63;
  float v = (Hf[(size_t)node*128 + lane]      + b2[lane])      * Wc[lane]
          + (Hf[(size_t)node*128 + 64 + lane] + b2[64 + lane]) * Wc[64 + lane];
  #pragma unroll
  for (int off = 32; off >= 1; off >>= 1) v += __shfl_xor(v, off);
  if (lane == 0) y[node] = 1.f / (1.f + __expf(-(v + bc[0])));
}

// ---- launcher --------------------------------------------------------------

extern "C" void kernel_launch(void* const* d_in, const int* in_sizes, int n_in,
                              void* d_out, int out_size, void* d_ws, size_t ws_size,
                              hipStream_t stream)
{
  const float* x   = (const float*)d_in[0];
  const int*   ei  = (const int*)d_in[1];
  // d_in[2] = edge_attr (unused, edge_dim=None)
  const float* W1  = (const float*)d_in[3];
  const float* as1 = (const float*)d_in[4];
  const float* ad1 = (const float*)d_in[5];
  const float* b1  = (const float*)d_in[6];
  const float* W2  = (const float*)d_in[7];
  const float* as2 = (const float*)d_in[8];
  const float* ad2 = (const float*)d_in[9];
  const float* b2  = (const float*)d_in[10];
  const float* Wc  = (const float*)d_in[11];
  const float* bc  = (const float*)d_in[12];
  float* y = (float*)d_out;

  char* w = (char*)d_ws;
  auto take = [&](size_t bytes)->char*{
    char* p = w; w += (bytes + 255) & ~(size_t)255; return p;
  };
  float*    A      = (float*)   take((size_t)NN*128*4);  // h (current layer)
  float*    B      = (float*)   take((size_t)NN*128*4);  // aggregated output
  float*    pbuf   = (float*)   take((size_t)ET*4*4);    // e then p per edge x head
  float*    As     = (float*)   take((size_t)NN*4*4);
  float*    Ad     = (float*)   take((size_t)NN*4*4);
  unsigned* menc   = (unsigned*)take((size_t)NN*4*4);    // segment max (encoded)
  float*    S      = (float*)   take((size_t)NN*4*4);    // segment sum
  int*      count  = (int*)     take((size_t)NN*4);
  int*      offs   = (int*)     take((size_t)NN*4);
  int*      cursor = (int*)     take((size_t)NN*4);
  int*      btot   = (int*)     take(64*4);
  int2*     csr    = (int2*)    take((size_t)ET*8);      // (src, edge_id) sorted by dst
  (void)ws_size; (void)in_sizes; (void)n_in; (void)out_size;

  const int EB  = (ET + 255)/256;
  const int NB4 = (NN + 3)/4;

  // CSR build (graph identical for both layers)
  hipMemsetAsync(count, 0, (size_t)NN*4, stream);
  k_hist   <<<EB, 256, 0, stream>>>(ei, count);
  k_scan1  <<<49, 1024, 0, stream>>>(count, offs, btot, NN);
  k_scan2  <<<1, 64, 0, stream>>>(btot, 49);
  k_scan3  <<<49, 1024, 0, stream>>>(offs, count, btot, cursor, NN);
  k_scatter<<<EB, 256, 0, stream>>>(ei, cursor, csr);

  // ---- layer 1 ----
  hipMemsetAsync(menc, 0, (size_t)NN*16, stream);  // 0 == encf(-inf-ish) identity
  hipMemsetAsync(S,    0, (size_t)NN*16, stream);
  k_gemm_att<<<512, 256, 0, stream>>>(x, nullptr, W1, as1, ad1, A, As, Ad);
  k_edge1   <<<EB, 256, 0, stream>>>(ei, As, Ad, pbuf, menc);
  k_edge2   <<<EB, 256, 0, stream>>>(ei, pbuf, menc, S);
  k_aggr    <<<NB4, 256, 0, stream>>>(csr, offs, count, A, pbuf, S, B);

  // ---- layer 2 ---- (input = B + b1, folded into GEMM staging)
  hipMemsetAsync(menc, 0, (size_t)NN*16, stream);
  hipMemsetAsync(S,    0, (size_t)NN*16, stream);
  k_gemm_att<<<512, 256, 0, stream>>>(B, b1, W2, as2, ad2, A, As, Ad);
  k_edge1   <<<EB, 256, 0, stream>>>(ei, As, Ad, pbuf, menc);
  k_edge2   <<<EB, 256, 0, stream>>>(ei, pbuf, menc, S);
  k_aggr    <<<NB4, 256, 0, stream>>>(csr, offs, count, A, pbuf, S, B);

  // ---- classifier ----
  k_cls<<<NB4, 256, 0, stream>>>(B, b2, Wc, bc, y);
}

// Round 3
// 631.691 us; speedup vs baseline: 1.9428x; 1.9428x over previous
//
#include <hip/hip_runtime.h>
#include <stdint.h>

// GAT (2-layer) + sigmoid classifier for MI355X.
// N=50000 nodes, E=800000 edges (+N self loops), 128 features, 4 heads x 32.
//
// R2: no float atomics anywhere. Softmax fused into the CSR-gather
// aggregation (online max/sum, butterfly combine). Register-tiled GEMM.

#define NN 50000
#define NE 800000
#define ET 850000  // NE + NN self-loops

__device__ __forceinline__ float lrelu(float v){ return v > 0.f ? v : 0.2f*v; }

// ---- CSR build -------------------------------------------------------------

__global__ void k_hist(const int* __restrict__ ei, int* __restrict__ count){
  int e = blockIdx.x*256 + threadIdx.x;
  if (e >= ET) return;
  int dst = (e < NE) ? ei[NE + e] : (e - NE);
  atomicAdd(&count[dst], 1);
}

__global__ void k_scan1(const int* __restrict__ count, int* __restrict__ incl,
                        int* __restrict__ btot, int n){
  __shared__ int sm[1024];
  int i = blockIdx.x*1024 + threadIdx.x;
  int v = (i < n) ? count[i] : 0;
  sm[threadIdx.x] = v;
  __syncthreads();
  for (int off = 1; off < 1024; off <<= 1){
    int t = (threadIdx.x >= off) ? sm[threadIdx.x - off] : 0;
    __syncthreads();
    sm[threadIdx.x] += t;
    __syncthreads();
  }
  if (i < n) incl[i] = sm[threadIdx.x];
  if (threadIdx.x == 1023) btot[blockIdx.x] = sm[1023];
}

__global__ void k_scan2(int* btot, int nb){  // single-wave exclusive scan
  int t = threadIdx.x;
  int orig = (t < nb) ? btot[t] : 0;
  int v = orig;
  for (int off = 1; off < 64; off <<= 1){
    int u = __shfl_up(v, off);
    if (t >= off) v += u;
  }
  if (t < nb) btot[t] = v - orig;
}

__global__ void k_scan3(int* __restrict__ offs_incl, const int* __restrict__ count,
                        const int* __restrict__ btot, int* __restrict__ cursor, int n){
  int i = blockIdx.x*1024 + threadIdx.x;
  if (i >= n) return;
  int excl = offs_incl[i] - count[i] + btot[blockIdx.x];
  offs_incl[i] = excl;   // in-place: incl -> excl
  cursor[i] = excl;
}

__global__ void k_scatter(const int* __restrict__ ei, int* __restrict__ cursor,
                          int* __restrict__ csr_src){
  int e = blockIdx.x*256 + threadIdx.x;
  if (e >= ET) return;
  int src, dst;
  if (e < NE){ src = ei[e]; dst = ei[NE + e]; } else { src = dst = e - NE; }
  int pos = atomicAdd(&cursor[dst], 1);
  csr_src[pos] = src;
}

// ---- GEMM (X @ W) fused with attention dot products ------------------------
// Block tile 64 rows x 128 cols; thread = 8 rows x 4 contiguous cols.
// W (64 KB) + X tile (32 KB) in LDS. Layer-2 input bias b1 folded as b1@W2.

__launch_bounds__(256)
__global__ void k_gemm_att(const float* __restrict__ X, const float* __restrict__ bias_in,
                           const float* __restrict__ W,
                           const float* __restrict__ att_s, const float* __restrict__ att_d,
                           float* __restrict__ Hout, float* __restrict__ As, float* __restrict__ Ad)
{
  __shared__ float Ws[128*128];   // 64 KB
  __shared__ float xs[64*128];    // 32 KB
  int tid  = threadIdx.x;
  int rowq = tid >> 5;            // 0..7  (8 rows each)
  int colq = tid & 31;            // 0..31 (4 cols each)
  int c0   = colq*4;

  // stage W: lane-contiguous 16B chunks, conflict-free
  for (int i = tid*4; i < 128*128; i += 256*4)
    *(float4*)&Ws[i] = *(const float4*)&W[i];
  __syncthreads();

  // bW = bias_in @ W (constant per column), folded into acc init
  float4 bW = make_float4(0.f,0.f,0.f,0.f);
  if (bias_in){
    for (int k = 0; k < 128; k++){
      float b = bias_in[k];
      float4 wv = *(float4*)&Ws[k*128 + c0];
      bW.x += b*wv.x; bW.y += b*wv.y; bW.z += b*wv.z; bW.w += b*wv.w;
    }
  }
  float4 atts = *(const float4*)&att_s[c0];
  float4 attd = *(const float4*)&att_d[c0];

  const int ntiles = (NN + 63)/64;
  for (int t = blockIdx.x; t < ntiles; t += gridDim.x){
    int base = t*64;
    // stage X tile: flat mapping, lane addr = tid*16B -> conflict-free, coalesced
    #pragma unroll
    for (int q = 0; q < 8; q++){
      int f = q*1024 + tid*4;          // flat float index into 64x128 tile
      int r = base + (f >> 7);
      if (r >= NN) r = NN-1;           // clamp tail (stores guarded below)
      *(float4*)&xs[f] = *(const float4*)&X[(size_t)r*128 + (f & 127)];
    }
    __syncthreads();

    float4 acc[8];
    #pragma unroll
    for (int i = 0; i < 8; i++) acc[i] = bW;

    for (int k = 0; k < 128; k += 4){
      float4 w0 = *(float4*)&Ws[(k+0)*128 + c0];
      float4 w1 = *(float4*)&Ws[(k+1)*128 + c0];
      float4 w2 = *(float4*)&Ws[(k+2)*128 + c0];
      float4 w3 = *(float4*)&Ws[(k+3)*128 + c0];
      #pragma unroll
      for (int i = 0; i < 8; i++){
        float4 xv = *(float4*)&xs[(rowq*8+i)*128 + k];
        acc[i].x += xv.x*w0.x + xv.y*w1.x + xv.z*w2.x + xv.w*w3.x;
        acc[i].y += xv.x*w0.y + xv.y*w1.y + xv.z*w2.y + xv.w*w3.y;
        acc[i].z += xv.x*w0.z + xv.y*w1.z + xv.z*w2.z + xv.w*w3.z;
        acc[i].w += xv.x*w0.w + xv.y*w1.w + xv.z*w2.w + xv.w*w3.w;
      }
    }

    #pragma unroll
    for (int i = 0; i < 8; i++){
      int row = base + rowq*8 + i;
      bool ok = row < NN;
      if (ok) *(float4*)&Hout[(size_t)row*128 + c0] = acc[i];
      // attention dots: reduce over the 8 threads (32 dims) of this head
      float ps = acc[i].x*atts.x + acc[i].y*atts.y + acc[i].z*atts.z + acc[i].w*atts.w;
      float pd = acc[i].x*attd.x + acc[i].y*attd.y + acc[i].z*attd.z + acc[i].w*attd.w;
      ps += __shfl_xor(ps,1); ps += __shfl_xor(ps,2); ps += __shfl_xor(ps,4);
      pd += __shfl_xor(pd,1); pd += __shfl_xor(pd,2); pd += __shfl_xor(pd,4);
      if (ok && (colq & 7) == 0){
        As[row*4 + (colq>>3)] = ps;
        Ad[row*4 + (colq>>3)] = pd;
      }
    }
    __syncthreads();  // xs reads done before next stage overwrites
  }
}

// ---- fused segment-softmax + aggregation (CSR gather, no atomics) ----------
// One wave per node. Phase 1: lane-parallel online softmax over incoming
// edges (per 4 heads) + butterfly combine. Phase 2: feature-parallel
// accumulation of alpha * h[src]; lane owns features {lane, lane+64}.

__launch_bounds__(256)
__global__ void k_aggr_sm(const int* __restrict__ csr_src, const int* __restrict__ offs,
                          const int* __restrict__ count, const float* __restrict__ Hin,
                          const float* __restrict__ As, const float* __restrict__ Ad,
                          float* __restrict__ Out)
{
  int node = blockIdx.x*4 + (threadIdx.x >> 6);
  if (node >= NN) return;
  int lane = threadIdx.x & 63;
  int start = offs[node];
  int cnt   = count[node];
  float4 ad = *(const float4*)&Ad[node*4];

  // phase 1: online (m, s) per head, lane-parallel over edges
  float4 m = make_float4(-1e30f,-1e30f,-1e30f,-1e30f);
  float4 s = make_float4(0.f,0.f,0.f,0.f);
  for (int i = lane; i < cnt; i += 64){
    int src = csr_src[start + i];
    float4 a = *(const float4*)&As[src*4];
    #define ONL(c) { float e = lrelu(a.c + ad.c); float nm = fmaxf(m.c, e); \
                     s.c = s.c*__expf(m.c - nm) + __expf(e - nm); m.c = nm; }
    ONL(x) ONL(y) ONL(z) ONL(w)
    #undef ONL
  }
  #pragma unroll
  for (int off = 32; off; off >>= 1){
    #define CMB(c) { float mo = __shfl_xor(m.c, off); float so = __shfl_xor(s.c, off); \
                     float nm = fmaxf(m.c, mo); \
                     s.c = s.c*__expf(m.c - nm) + so*__expf(mo - nm); m.c = nm; }
    CMB(x) CMB(y) CMB(z) CMB(w)
    #undef CMB
  }

  // phase 2: feature-parallel; lane's heads are (lane>>5) and 2+(lane>>5)
  bool hi = (lane & 32) != 0;
  float mA = hi ? m.y : m.x;
  float mB = hi ? m.w : m.z;
  float rA = 1.f / ((hi ? s.y : s.x) + 1e-16f);
  float rB = 1.f / ((hi ? s.w : s.z) + 1e-16f);
  float acc0 = 0.f, acc1 = 0.f;
  for (int i = 0; i < cnt; i++){
    int src = csr_src[start + i];                  // broadcast, L1-hot
    float4 a = *(const float4*)&As[src*4];         // broadcast, L1/L2-hot
    float eA = hi ? lrelu(a.y + ad.y) : lrelu(a.x + ad.x);
    float eB = hi ? lrelu(a.w + ad.w) : lrelu(a.z + ad.z);
    float aA = __expf(eA - mA) * rA;
    float aB = __expf(eB - mB) * rB;
    const float* hrow = &Hin[(size_t)src*128];     // 2x 256B coalesced
    acc0 += aA * hrow[lane];
    acc1 += aB * hrow[64 + lane];
  }
  Out[(size_t)node*128 + lane]      = acc0;
  Out[(size_t)node*128 + 64 + lane] = acc1;
}

// ---- classifier: sigmoid((h+b2) @ Wc + bc) ---------------------------------

__global__ void k_cls(const float* __restrict__ Hf, const float* __restrict__ b2,
                      const float* __restrict__ Wc, const float* __restrict__ bc,
                      float* __restrict__ y)
{
  int node = blockIdx.x*4 + (threadIdx.x >> 6);
  if (node >= NN) return;
  int lane = threadIdx.x & 63;
  float v = (Hf[(size_t)node*128 + lane]      + b2[lane])      * Wc[lane]
          + (Hf[(size_t)node*128 + 64 + lane] + b2[64 + lane]) * Wc[64 + lane];
  #pragma unroll
  for (int off = 32; off >= 1; off >>= 1) v += __shfl_xor(v, off);
  if (lane == 0) y[node] = 1.f / (1.f + __expf(-(v + bc[0])));
}

// ---- launcher --------------------------------------------------------------

extern "C" void kernel_launch(void* const* d_in, const int* in_sizes, int n_in,
                              void* d_out, int out_size, void* d_ws, size_t ws_size,
                              hipStream_t stream)
{
  const float* x   = (const float*)d_in[0];
  const int*   ei  = (const int*)d_in[1];
  // d_in[2] = edge_attr (unused, edge_dim=None)
  const float* W1  = (const float*)d_in[3];
  const float* as1 = (const float*)d_in[4];
  const float* ad1 = (const float*)d_in[5];
  const float* b1  = (const float*)d_in[6];
  const float* W2  = (const float*)d_in[7];
  const float* as2 = (const float*)d_in[8];
  const float* ad2 = (const float*)d_in[9];
  const float* b2  = (const float*)d_in[10];
  const float* Wc  = (const float*)d_in[11];
  const float* bc  = (const float*)d_in[12];
  float* y = (float*)d_out;

  char* w = (char*)d_ws;
  auto take = [&](size_t bytes)->char*{
    char* p = w; w += (bytes + 255) & ~(size_t)255; return p;
  };
  float* A      = (float*)take((size_t)NN*128*4);  // h (current layer)
  float* B      = (float*)take((size_t)NN*128*4);  // aggregated output
  float* As     = (float*)take((size_t)NN*4*4);
  float* Ad     = (float*)take((size_t)NN*4*4);
  int*   count  = (int*)  take((size_t)NN*4);
  int*   offs   = (int*)  take((size_t)NN*4);
  int*   cursor = (int*)  take((size_t)NN*4);
  int*   btot   = (int*)  take(64*4);
  int*   csr    = (int*)  take((size_t)ET*4);      // src per CSR slot (sorted by dst)
  (void)ws_size; (void)in_sizes; (void)n_in; (void)out_size;

  const int EB  = (ET + 255)/256;
  const int NB4 = (NN + 3)/4;

  // CSR build (graph identical for both layers)
  hipMemsetAsync(count, 0, (size_t)NN*4, stream);
  k_hist   <<<EB, 256, 0, stream>>>(ei, count);
  k_scan1  <<<49, 1024, 0, stream>>>(count, offs, btot, NN);
  k_scan2  <<<1, 64, 0, stream>>>(btot, 49);
  k_scan3  <<<49, 1024, 0, stream>>>(offs, count, btot, cursor, NN);
  k_scatter<<<EB, 256, 0, stream>>>(ei, cursor, csr);

  // ---- layer 1 ----
  k_gemm_att<<<256, 256, 0, stream>>>(x, nullptr, W1, as1, ad1, A, As, Ad);
  k_aggr_sm <<<NB4, 256, 0, stream>>>(csr, offs, count, A, As, Ad, B);

  // ---- layer 2 ---- (input bias b1 folded as b1@W2 inside the GEMM)
  k_gemm_att<<<256, 256, 0, stream>>>(B, b1, W2, as2, ad2, A, As, Ad);
  k_aggr_sm <<<NB4, 256, 0, stream>>>(csr, offs, count, A, As, Ad, B);

  // ---- classifier ----
  k_cls<<<NB4, 256, 0, stream>>>(B, b2, Wc, bc, y);
}

// Round 4
// 428.219 us; speedup vs baseline: 2.8660x; 1.4752x over previous
//
#include <hip/hip_runtime.h>
#include <stdint.h>

// GAT (2-layer) + sigmoid classifier for MI355X.
// N=50000 nodes, E=800000 edges (+N self loops), 128 features, 4 heads x 32.
//
// R4: alpha computed once per edge (exact 2-pass softmax, LDS-cached),
// lean 2-edge-per-iteration gather loop, classifier fused into layer-2
// aggregation (h2 never materialized).

#define NN 50000
#define NE 800000
#define ET 850000   // NE + NN self-loops
#define DCAP 128    // LDS alpha slots per node (Poisson(17) degrees; fallback path beyond)

__device__ __forceinline__ float lrelu(float v){ return v > 0.f ? v : 0.2f*v; }

// ---- CSR build -------------------------------------------------------------

__global__ void k_hist(const int* __restrict__ ei, int* __restrict__ count){
  int e = blockIdx.x*256 + threadIdx.x;
  if (e >= ET) return;
  int dst = (e < NE) ? ei[NE + e] : (e - NE);
  atomicAdd(&count[dst], 1);
}

__global__ void k_scan1(const int* __restrict__ count, int* __restrict__ incl,
                        int* __restrict__ btot, int n){
  __shared__ int sm[1024];
  int i = blockIdx.x*1024 + threadIdx.x;
  int v = (i < n) ? count[i] : 0;
  sm[threadIdx.x] = v;
  __syncthreads();
  for (int off = 1; off < 1024; off <<= 1){
    int t = (threadIdx.x >= off) ? sm[threadIdx.x - off] : 0;
    __syncthreads();
    sm[threadIdx.x] += t;
    __syncthreads();
  }
  if (i < n) incl[i] = sm[threadIdx.x];
  if (threadIdx.x == 1023) btot[blockIdx.x] = sm[1023];
}

__global__ void k_scan2(int* btot, int nb){  // single-wave exclusive scan
  int t = threadIdx.x;
  int orig = (t < nb) ? btot[t] : 0;
  int v = orig;
  for (int off = 1; off < 64; off <<= 1){
    int u = __shfl_up(v, off);
    if (t >= off) v += u;
  }
  if (t < nb) btot[t] = v - orig;
}

__global__ void k_scan3(int* __restrict__ offs_incl, const int* __restrict__ count,
                        const int* __restrict__ btot, int* __restrict__ cursor, int n){
  int i = blockIdx.x*1024 + threadIdx.x;
  if (i >= n) return;
  int excl = offs_incl[i] - count[i] + btot[blockIdx.x];
  offs_incl[i] = excl;   // in-place: incl -> excl
  cursor[i] = excl;
}

__global__ void k_scatter(const int* __restrict__ ei, int* __restrict__ cursor,
                          int* __restrict__ csr_src){
  int e = blockIdx.x*256 + threadIdx.x;
  if (e >= ET) return;
  int src, dst;
  if (e < NE){ src = ei[e]; dst = ei[NE + e]; } else { src = dst = e - NE; }
  int pos = atomicAdd(&cursor[dst], 1);
  csr_src[pos] = src;
}

// ---- GEMM (X @ W) fused with attention dot products ------------------------
// Block tile 64 rows x 128 cols; thread = 8 rows x 4 contiguous cols.
// W (64 KB) + X tile (32 KB) in LDS. Layer-2 input bias b1 folded as b1@W2.

__launch_bounds__(256)
__global__ void k_gemm_att(const float* __restrict__ X, const float* __restrict__ bias_in,
                           const float* __restrict__ W,
                           const float* __restrict__ att_s, const float* __restrict__ att_d,
                           float* __restrict__ Hout, float* __restrict__ As, float* __restrict__ Ad)
{
  __shared__ float Ws[128*128];   // 64 KB
  __shared__ float xs[64*128];    // 32 KB
  int tid  = threadIdx.x;
  int rowq = tid >> 5;            // 0..7  (8 rows each)
  int colq = tid & 31;            // 0..31 (4 cols each)
  int c0   = colq*4;

  for (int i = tid*4; i < 128*128; i += 256*4)
    *(float4*)&Ws[i] = *(const float4*)&W[i];
  __syncthreads();

  float4 bW = make_float4(0.f,0.f,0.f,0.f);
  if (bias_in){
    for (int k = 0; k < 128; k++){
      float b = bias_in[k];
      float4 wv = *(float4*)&Ws[k*128 + c0];
      bW.x += b*wv.x; bW.y += b*wv.y; bW.z += b*wv.z; bW.w += b*wv.w;
    }
  }
  float4 atts = *(const float4*)&att_s[c0];
  float4 attd = *(const float4*)&att_d[c0];

  const int ntiles = (NN + 63)/64;
  for (int t = blockIdx.x; t < ntiles; t += gridDim.x){
    int base = t*64;
    #pragma unroll
    for (int q = 0; q < 8; q++){
      int f = q*1024 + tid*4;
      int r = base + (f >> 7);
      if (r >= NN) r = NN-1;
      *(float4*)&xs[f] = *(const float4*)&X[(size_t)r*128 + (f & 127)];
    }
    __syncthreads();

    float4 acc[8];
    #pragma unroll
    for (int i = 0; i < 8; i++) acc[i] = bW;

    for (int k = 0; k < 128; k += 4){
      float4 w0 = *(float4*)&Ws[(k+0)*128 + c0];
      float4 w1 = *(float4*)&Ws[(k+1)*128 + c0];
      float4 w2 = *(float4*)&Ws[(k+2)*128 + c0];
      float4 w3 = *(float4*)&Ws[(k+3)*128 + c0];
      #pragma unroll
      for (int i = 0; i < 8; i++){
        float4 xv = *(float4*)&xs[(rowq*8+i)*128 + k];
        acc[i].x += xv.x*w0.x + xv.y*w1.x + xv.z*w2.x + xv.w*w3.x;
        acc[i].y += xv.x*w0.y + xv.y*w1.y + xv.z*w2.y + xv.w*w3.y;
        acc[i].z += xv.x*w0.z + xv.y*w1.z + xv.z*w2.z + xv.w*w3.z;
        acc[i].w += xv.x*w0.w + xv.y*w1.w + xv.z*w2.w + xv.w*w3.w;
      }
    }

    #pragma unroll
    for (int i = 0; i < 8; i++){
      int row = base + rowq*8 + i;
      bool ok = row < NN;
      if (ok) *(float4*)&Hout[(size_t)row*128 + c0] = acc[i];
      float ps = acc[i].x*atts.x + acc[i].y*atts.y + acc[i].z*atts.z + acc[i].w*atts.w;
      float pd = acc[i].x*attd.x + acc[i].y*attd.y + acc[i].z*attd.z + acc[i].w*attd.w;
      ps += __shfl_xor(ps,1); ps += __shfl_xor(ps,2); ps += __shfl_xor(ps,4);
      pd += __shfl_xor(pd,1); pd += __shfl_xor(pd,2); pd += __shfl_xor(pd,4);
      if (ok && (colq & 7) == 0){
        As[row*4 + (colq>>3)] = ps;
        Ad[row*4 + (colq>>3)] = pd;
      }
    }
    __syncthreads();
  }
}

// ---- fused softmax + aggregation (+ optional classifier epilogue) ----------
// One wave per node (4 nodes / 256-thread block). Fast path (cnt <= DCAP):
//   pass A: per-lane e (4 heads), butterfly max  -> exact segment max
//   pass B: p = exp(e-m), butterfly sum, alpha = p/(s+eps) -> LDS
//   phase 2: 2 edges/iter; half-wave w takes edge i+w; lane loads float4 of
//            h[src]; alpha via LDS broadcast; cross-half shfl reduce at end.
// CLS=1: compute sigmoid((acc + bias) . Wc + bc) instead of storing the row.

template<int CLS>
__launch_bounds__(256)
__global__ void k_aggr2(const int* __restrict__ csr_src, const int* __restrict__ offs,
                        const int* __restrict__ count, const float* __restrict__ Hin,
                        const float* __restrict__ As, const float* __restrict__ Ad,
                        float* __restrict__ Out,
                        const float* __restrict__ bias, const float* __restrict__ Wc,
                        const float* __restrict__ bc)
{
  __shared__ float al[4][4][DCAP];  // [wave][head][edge] : 8 KB
  __shared__ int   sl[4][DCAP];     // [wave][edge]       : 2 KB
  int wid  = threadIdx.x >> 6;
  int lane = threadIdx.x & 63;
  int node = blockIdx.x*4 + wid;
  bool valid = node < NN;
  int start = valid ? offs[node]  : 0;
  int cnt   = valid ? count[node] : 0;
  float4 ad4 = valid ? *(const float4*)&Ad[(size_t)node*4] : make_float4(0,0,0,0);
  bool fast = (cnt <= DCAP);

  if (valid && fast){
    float4 e0 = make_float4(0,0,0,0), e1 = make_float4(0,0,0,0);
    int s0 = -1, s1 = -1;
    float4 m = make_float4(-1e30f,-1e30f,-1e30f,-1e30f);
    if (lane < cnt){
      s0 = csr_src[start + lane];
      float4 a = *(const float4*)&As[(size_t)s0*4];
      e0.x = lrelu(a.x+ad4.x); e0.y = lrelu(a.y+ad4.y);
      e0.z = lrelu(a.z+ad4.z); e0.w = lrelu(a.w+ad4.w);
      m = e0;
    }
    if (lane + 64 < cnt){
      s1 = csr_src[start + lane + 64];
      float4 a = *(const float4*)&As[(size_t)s1*4];
      e1.x = lrelu(a.x+ad4.x); e1.y = lrelu(a.y+ad4.y);
      e1.z = lrelu(a.z+ad4.z); e1.w = lrelu(a.w+ad4.w);
      m.x = fmaxf(m.x, e1.x); m.y = fmaxf(m.y, e1.y);
      m.z = fmaxf(m.z, e1.z); m.w = fmaxf(m.w, e1.w);
    }
    #pragma unroll
    for (int off = 32; off; off >>= 1){
      m.x = fmaxf(m.x, __shfl_xor(m.x, off));
      m.y = fmaxf(m.y, __shfl_xor(m.y, off));
      m.z = fmaxf(m.z, __shfl_xor(m.z, off));
      m.w = fmaxf(m.w, __shfl_xor(m.w, off));
    }
    float4 p0 = make_float4(0,0,0,0), p1 = make_float4(0,0,0,0);
    if (s0 >= 0){
      p0.x = __expf(e0.x - m.x); p0.y = __expf(e0.y - m.y);
      p0.z = __expf(e0.z - m.z); p0.w = __expf(e0.w - m.w);
    }
    if (s1 >= 0){
      p1.x = __expf(e1.x - m.x); p1.y = __expf(e1.y - m.y);
      p1.z = __expf(e1.z - m.z); p1.w = __expf(e1.w - m.w);
    }
    float4 s4 = make_float4(p0.x+p1.x, p0.y+p1.y, p0.z+p1.z, p0.w+p1.w);
    #pragma unroll
    for (int off = 32; off; off >>= 1){
      s4.x += __shfl_xor(s4.x, off);
      s4.y += __shfl_xor(s4.y, off);
      s4.z += __shfl_xor(s4.z, off);
      s4.w += __shfl_xor(s4.w, off);
    }
    float4 r4 = make_float4(1.f/(s4.x+1e-16f), 1.f/(s4.y+1e-16f),
                            1.f/(s4.z+1e-16f), 1.f/(s4.w+1e-16f));
    if (s0 >= 0){
      al[wid][0][lane] = p0.x*r4.x; al[wid][1][lane] = p0.y*r4.y;
      al[wid][2][lane] = p0.z*r4.z; al[wid][3][lane] = p0.w*r4.w;
      sl[wid][lane] = s0;
    }
    if (s1 >= 0){
      al[wid][0][lane+64] = p1.x*r4.x; al[wid][1][lane+64] = p1.y*r4.y;
      al[wid][2][lane+64] = p1.z*r4.z; al[wid][3][lane+64] = p1.w*r4.w;
      sl[wid][lane+64] = s1;
    }
  }
  __syncthreads();
  if (!valid) return;

  if (fast){
    int half = lane >> 5;
    int q    = lane & 31;   // feature quad: features q*4 .. q*4+3
    int hsel = q >> 3;      // owning head
    float4 acc = make_float4(0,0,0,0);
    for (int i = 0; i < cnt; i += 2){
      int e = i + half;
      bool ev = e < cnt;
      int eidx = ev ? e : (cnt-1);
      float a  = ev ? al[wid][hsel][eidx] : 0.f;
      int src  = sl[wid][eidx];
      float4 hv = ((const float4*)&Hin[(size_t)src*128])[q];
      acc.x += a*hv.x; acc.y += a*hv.y; acc.z += a*hv.z; acc.w += a*hv.w;
    }
    acc.x += __shfl_xor(acc.x, 32);
    acc.y += __shfl_xor(acc.y, 32);
    acc.z += __shfl_xor(acc.z, 32);
    acc.w += __shfl_xor(acc.w, 32);
    if (CLS){
      float4 b  = *(const float4*)&bias[q*4];
      float4 wc = *(const float4*)&Wc[q*4];
      float v = (acc.x+b.x)*wc.x + (acc.y+b.y)*wc.y
              + (acc.z+b.z)*wc.z + (acc.w+b.w)*wc.w;
      v += __shfl_xor(v,1); v += __shfl_xor(v,2); v += __shfl_xor(v,4);
      v += __shfl_xor(v,8); v += __shfl_xor(v,16);
      if (lane == 0) Out[node] = 1.f/(1.f + __expf(-(v + bc[0])));
    } else {
      if (lane < 32) ((float4*)&Out[(size_t)node*128])[q] = acc;
    }
  } else {
    // ---- slow fallback (cnt > DCAP): online softmax + recompute ----
    float4 m = make_float4(-1e30f,-1e30f,-1e30f,-1e30f);
    float4 s = make_float4(0.f,0.f,0.f,0.f);
    for (int i = lane; i < cnt; i += 64){
      int src = csr_src[start + i];
      float4 a = *(const float4*)&As[(size_t)src*4];
      #define ONL(c) { float e = lrelu(a.c + ad4.c); float nm = fmaxf(m.c, e); \
                       s.c = s.c*__expf(m.c - nm) + __expf(e - nm); m.c = nm; }
      ONL(x) ONL(y) ONL(z) ONL(w)
      #undef ONL
    }
    #pragma unroll
    for (int off = 32; off; off >>= 1){
      #define CMB(c) { float mo = __shfl_xor(m.c, off); float so = __shfl_xor(s.c, off); \
                       float nm = fmaxf(m.c, mo); \
                       s.c = s.c*__expf(m.c - nm) + so*__expf(mo - nm); m.c = nm; }
      CMB(x) CMB(y) CMB(z) CMB(w)
      #undef CMB
    }
    bool hi = (lane & 32) != 0;
    float mA = hi ? m.y : m.x;
    float mB = hi ? m.w : m.z;
    float rA = 1.f / ((hi ? s.y : s.x) + 1e-16f);
    float rB = 1.f / ((hi ? s.w : s.z) + 1e-16f);
    float acc0 = 0.f, acc1 = 0.f;
    for (int i = 0; i < cnt; i++){
      int src = csr_src[start + i];
      float4 a = *(const float4*)&As[(size_t)src*4];
      float eA = hi ? lrelu(a.y + ad4.y) : lrelu(a.x + ad4.x);
      float eB = hi ? lrelu(a.w + ad4.w) : lrelu(a.z + ad4.z);
      float aA = __expf(eA - mA) * rA;
      float aB = __expf(eB - mB) * rB;
      const float* hrow = &Hin[(size_t)src*128];
      acc0 += aA * hrow[lane];
      acc1 += aB * hrow[64 + lane];
    }
    if (CLS){
      float v = (acc0 + bias[lane])*Wc[lane] + (acc1 + bias[64+lane])*Wc[64+lane];
      #pragma unroll
      for (int off = 32; off >= 1; off >>= 1) v += __shfl_xor(v, off);
      if (lane == 0) Out[node] = 1.f/(1.f + __expf(-(v + bc[0])));
    } else {
      Out[(size_t)node*128 + lane]      = acc0;
      Out[(size_t)node*128 + 64 + lane] = acc1;
    }
  }
}

// ---- launcher --------------------------------------------------------------

extern "C" void kernel_launch(void* const* d_in, const int* in_sizes, int n_in,
                              void* d_out, int out_size, void* d_ws, size_t ws_size,
                              hipStream_t stream)
{
  const float* x   = (const float*)d_in[0];
  const int*   ei  = (const int*)d_in[1];
  // d_in[2] = edge_attr (unused, edge_dim=None)
  const float* W1  = (const float*)d_in[3];
  const float* as1 = (const float*)d_in[4];
  const float* ad1 = (const float*)d_in[5];
  const float* b1  = (const float*)d_in[6];
  const float* W2  = (const float*)d_in[7];
  const float* as2 = (const float*)d_in[8];
  const float* ad2 = (const float*)d_in[9];
  const float* b2  = (const float*)d_in[10];
  const float* Wc  = (const float*)d_in[11];
  const float* bc  = (const float*)d_in[12];
  float* y = (float*)d_out;

  char* w = (char*)d_ws;
  auto take = [&](size_t bytes)->char*{
    char* p = w; w += (bytes + 255) & ~(size_t)255; return p;
  };
  float* A      = (float*)take((size_t)NN*128*4);  // h (current layer)
  float* B      = (float*)take((size_t)NN*128*4);  // layer-1 aggregated output
  float* As     = (float*)take((size_t)NN*4*4);
  float* Ad     = (float*)take((size_t)NN*4*4);
  int*   count  = (int*)  take((size_t)NN*4);
  int*   offs   = (int*)  take((size_t)NN*4);
  int*   cursor = (int*)  take((size_t)NN*4);
  int*   btot   = (int*)  take(64*4);
  int*   csr    = (int*)  take((size_t)ET*4);      // src per CSR slot (sorted by dst)
  (void)ws_size; (void)in_sizes; (void)n_in; (void)out_size;

  const int EB  = (ET + 255)/256;
  const int NB4 = (NN + 3)/4;

  // CSR build (graph identical for both layers)
  hipMemsetAsync(count, 0, (size_t)NN*4, stream);
  k_hist   <<<EB, 256, 0, stream>>>(ei, count);
  k_scan1  <<<49, 1024, 0, stream>>>(count, offs, btot, NN);
  k_scan2  <<<1, 64, 0, stream>>>(btot, 49);
  k_scan3  <<<49, 1024, 0, stream>>>(offs, count, btot, cursor, NN);
  k_scatter<<<EB, 256, 0, stream>>>(ei, cursor, csr);

  // ---- layer 1 ----
  k_gemm_att<<<256, 256, 0, stream>>>(x, nullptr, W1, as1, ad1, A, As, Ad);
  k_aggr2<0><<<NB4, 256, 0, stream>>>(csr, offs, count, A, As, Ad, B,
                                      nullptr, nullptr, nullptr);

  // ---- layer 2 ---- (input bias b1 folded as b1@W2; classifier fused)
  k_gemm_att<<<256, 256, 0, stream>>>(B, b1, W2, as2, ad2, A, As, Ad);
  k_aggr2<1><<<NB4, 256, 0, stream>>>(csr, offs, count, A, As, Ad, y,
                                      b2, Wc, bc);
}

// Round 7
// 406.773 us; speedup vs baseline: 3.0171x; 1.0527x over previous
//
#include <hip/hip_runtime.h>
#include <stdint.h>

// GAT (2-layer) + sigmoid classifier for MI355X.
// N=50000 nodes, E=800000 edges (+N self loops), 128 features, 4 heads x 32.
//
// R5: aggr2 conflict-free alpha layout [wave][edge][head] + 4-edge unrolled
// gather loop (2 rows in flight). GEMM at 2 blocks/CU (80 KB LDS, BM=32).

#define NN 50000
#define NE 800000
#define ET 850000   // NE + NN self-loops
#define DCAP 128    // LDS alpha slots per node (Poisson(17) degrees; fallback beyond)

__device__ __forceinline__ float lrelu(float v){ return v > 0.f ? v : 0.2f*v; }

// ---- CSR build -------------------------------------------------------------

__global__ void k_hist(const int* __restrict__ ei, int* __restrict__ count){
  int e = blockIdx.x*256 + threadIdx.x;
  if (e >= ET) return;
  int dst = (e < NE) ? ei[NE + e] : (e - NE);
  atomicAdd(&count[dst], 1);
}

__global__ void k_scan1(const int* __restrict__ count, int* __restrict__ incl,
                        int* __restrict__ btot, int n){
  __shared__ int sm[1024];
  int i = blockIdx.x*1024 + threadIdx.x;
  int v = (i < n) ? count[i] : 0;
  sm[threadIdx.x] = v;
  __syncthreads();
  for (int off = 1; off < 1024; off <<= 1){
    int t = (threadIdx.x >= off) ? sm[threadIdx.x - off] : 0;
    __syncthreads();
    sm[threadIdx.x] += t;
    __syncthreads();
  }
  if (i < n) incl[i] = sm[threadIdx.x];
  if (threadIdx.x == 1023) btot[blockIdx.x] = sm[1023];
}

__global__ void k_scan2(int* btot, int nb){  // single-wave exclusive scan
  int t = threadIdx.x;
  int orig = (t < nb) ? btot[t] : 0;
  int v = orig;
  for (int off = 1; off < 64; off <<= 1){
    int u = __shfl_up(v, off);
    if (t >= off) v += u;
  }
  if (t < nb) btot[t] = v - orig;
}

__global__ void k_scan3(int* __restrict__ offs_incl, const int* __restrict__ count,
                        const int* __restrict__ btot, int* __restrict__ cursor, int n){
  int i = blockIdx.x*1024 + threadIdx.x;
  if (i >= n) return;
  int excl = offs_incl[i] - count[i] + btot[blockIdx.x];
  offs_incl[i] = excl;   // in-place: incl -> excl
  cursor[i] = excl;
}

__global__ void k_scatter(const int* __restrict__ ei, int* __restrict__ cursor,
                          int* __restrict__ csr_src){
  int e = blockIdx.x*256 + threadIdx.x;
  if (e >= ET) return;
  int src, dst;
  if (e < NE){ src = ei[e]; dst = ei[NE + e]; } else { src = dst = e - NE; }
  int pos = atomicAdd(&cursor[dst], 1);
  csr_src[pos] = src;
}

// ---- GEMM (X @ W) fused with attention dot products ------------------------
// Block tile 32 rows x 128 cols; thread = 4 rows x 4 contiguous cols.
// LDS: W 64 KB + X tile 16 KB = 80 KB -> 2 blocks/CU (8 waves/CU).
// Layer-2 input bias b1 folded as (b1 @ W2) into the accumulator init.

__launch_bounds__(256, 2)
__global__ void k_gemm_att(const float* __restrict__ X, const float* __restrict__ bias_in,
                           const float* __restrict__ W,
                           const float* __restrict__ att_s, const float* __restrict__ att_d,
                           float* __restrict__ Hout, float* __restrict__ As, float* __restrict__ Ad)
{
  __shared__ float Ws[128*128];   // 64 KB
  __shared__ float xs[32*128];    // 16 KB
  int tid  = threadIdx.x;
  int rowq = tid >> 5;            // 0..7  (4 rows each)
  int colq = tid & 31;            // 0..31 (4 cols each)
  int c0   = colq*4;

  for (int i = tid*4; i < 128*128; i += 256*4)
    *(float4*)&Ws[i] = *(const float4*)&W[i];
  __syncthreads();

  float4 bW = make_float4(0.f,0.f,0.f,0.f);
  if (bias_in){
    for (int k = 0; k < 128; k++){
      float b = bias_in[k];
      float4 wv = *(float4*)&Ws[k*128 + c0];
      bW.x += b*wv.x; bW.y += b*wv.y; bW.z += b*wv.z; bW.w += b*wv.w;
    }
  }
  float4 atts = *(const float4*)&att_s[c0];
  float4 attd = *(const float4*)&att_d[c0];

  const int ntiles = (NN + 31)/32;
  for (int t = blockIdx.x; t < ntiles; t += gridDim.x){
    int base = t*32;
    // stage X tile: 1024 float4, 256 threads -> 4 each; coalesced, conflict-free
    #pragma unroll
    for (int q = 0; q < 4; q++){
      int f = q*1024 + tid*4;          // flat float index into 32x128 tile
      int r = base + (f >> 7);
      if (r >= NN) r = NN-1;           // clamp tail (stores guarded below)
      *(float4*)&xs[f] = *(const float4*)&X[(size_t)r*128 + (f & 127)];
    }
    __syncthreads();

    float4 acc[4];
    #pragma unroll
    for (int i = 0; i < 4; i++) acc[i] = bW;

    for (int k = 0; k < 128; k += 4){
      float4 w0 = *(float4*)&Ws[(k+0)*128 + c0];
      float4 w1 = *(float4*)&Ws[(k+1)*128 + c0];
      float4 w2 = *(float4*)&Ws[(k+2)*128 + c0];
      float4 w3 = *(float4*)&Ws[(k+3)*128 + c0];
      #pragma unroll
      for (int i = 0; i < 4; i++){
        float4 xv = *(float4*)&xs[(rowq*4+i)*128 + k];
        acc[i].x += xv.x*w0.x + xv.y*w1.x + xv.z*w2.x + xv.w*w3.x;
        acc[i].y += xv.x*w0.y + xv.y*w1.y + xv.z*w2.y + xv.w*w3.y;
        acc[i].z += xv.x*w0.z + xv.y*w1.z + xv.z*w2.z + xv.w*w3.z;
        acc[i].w += xv.x*w0.w + xv.y*w1.w + xv.z*w2.w + xv.w*w3.w;
      }
    }

    #pragma unroll
    for (int i = 0; i < 4; i++){
      int row = base + rowq*4 + i;
      bool ok = row < NN;
      if (ok) *(float4*)&Hout[(size_t)row*128 + c0] = acc[i];
      // attention dots: reduce over the 8 threads (32 dims) of this head
      float ps = acc[i].x*atts.x + acc[i].y*atts.y + acc[i].z*atts.z + acc[i].w*atts.w;
      float pd = acc[i].x*attd.x + acc[i].y*attd.y + acc[i].z*attd.z + acc[i].w*attd.w;
      ps += __shfl_xor(ps,1); ps += __shfl_xor(ps,2); ps += __shfl_xor(ps,4);
      pd += __shfl_xor(pd,1); pd += __shfl_xor(pd,2); pd += __shfl_xor(pd,4);
      if (ok && (colq & 7) == 0){
        As[row*4 + (colq>>3)] = ps;
        Ad[row*4 + (colq>>3)] = pd;
      }
    }
    __syncthreads();
  }
}

// ---- fused softmax + aggregation (+ optional classifier epilogue) ----------
// One wave per node (4 nodes / 256-thread block). Fast path (cnt <= DCAP):
//   pass A: per-lane e (4 heads), butterfly max -> exp -> butterfly sum;
//           alpha -> LDS laid out [wave][edge][head] (conflict-free reads).
//   phase 2: 4 edges/iter; half-wave takes edges {i+half, i+2+half}; both
//            h-row float4 loads issued before use; cross-half reduce at end.
// CLS=1: compute sigmoid((acc + bias) . Wc + bc) instead of storing the row.

template<int CLS>
__launch_bounds__(256)
__global__ void k_aggr2(const int* __restrict__ csr_src, const int* __restrict__ offs,
                        const int* __restrict__ count, const float* __restrict__ Hin,
                        const float* __restrict__ As, const float* __restrict__ Ad,
                        float* __restrict__ Out,
                        const float* __restrict__ bias, const float* __restrict__ Wc,
                        const float* __restrict__ bc)
{
  __shared__ float al[4][DCAP][4];  // [wave][edge][head] : 8 KB, conflict-free
  __shared__ int   sl[4][DCAP];     // [wave][edge]       : 2 KB
  int wid  = threadIdx.x >> 6;
  int lane = threadIdx.x & 63;
  int node = blockIdx.x*4 + wid;
  bool valid = node < NN;
  int start = valid ? offs[node]  : 0;
  int cnt   = valid ? count[node] : 0;
  float4 ad4 = valid ? *(const float4*)&Ad[(size_t)node*4] : make_float4(0,0,0,0);
  bool fast = (cnt <= DCAP);

  if (valid && fast){
    float4 e0 = make_float4(0,0,0,0), e1 = make_float4(0,0,0,0);
    int s0 = -1, s1 = -1;
    float4 m = make_float4(-1e30f,-1e30f,-1e30f,-1e30f);
    if (lane < cnt){
      s0 = csr_src[start + lane];
      float4 a = *(const float4*)&As[(size_t)s0*4];
      e0.x = lrelu(a.x+ad4.x); e0.y = lrelu(a.y+ad4.y);
      e0.z = lrelu(a.z+ad4.z); e0.w = lrelu(a.w+ad4.w);
      m = e0;
    }
    if (lane + 64 < cnt){
      s1 = csr_src[start + lane + 64];
      float4 a = *(const float4*)&As[(size_t)s1*4];
      e1.x = lrelu(a.x+ad4.x); e1.y = lrelu(a.y+ad4.y);
      e1.z = lrelu(a.z+ad4.z); e1.w = lrelu(a.w+ad4.w);
      m.x = fmaxf(m.x, e1.x); m.y = fmaxf(m.y, e1.y);
      m.z = fmaxf(m.z, e1.z); m.w = fmaxf(m.w, e1.w);
    }
    #pragma unroll
    for (int off = 32; off; off >>= 1){
      m.x = fmaxf(m.x, __shfl_xor(m.x, off));
      m.y = fmaxf(m.y, __shfl_xor(m.y, off));
      m.z = fmaxf(m.z, __shfl_xor(m.z, off));
      m.w = fmaxf(m.w, __shfl_xor(m.w, off));
    }
    float4 p0 = make_float4(0,0,0,0), p1 = make_float4(0,0,0,0);
    if (s0 >= 0){
      p0.x = __expf(e0.x - m.x); p0.y = __expf(e0.y - m.y);
      p0.z = __expf(e0.z - m.z); p0.w = __expf(e0.w - m.w);
    }
    if (s1 >= 0){
      p1.x = __expf(e1.x - m.x); p1.y = __expf(e1.y - m.y);
      p1.z = __expf(e1.z - m.z); p1.w = __expf(e1.w - m.w);
    }
    float4 s4 = make_float4(p0.x+p1.x, p0.y+p1.y, p0.z+p1.z, p0.w+p1.w);
    #pragma unroll
    for (int off = 32; off; off >>= 1){
      s4.x += __shfl_xor(s4.x, off);
      s4.y += __shfl_xor(s4.y, off);
      s4.z += __shfl_xor(s4.z, off);
      s4.w += __shfl_xor(s4.w, off);
    }
    float4 r4 = make_float4(1.f/(s4.x+1e-16f), 1.f/(s4.y+1e-16f),
                            1.f/(s4.z+1e-16f), 1.f/(s4.w+1e-16f));
    if (s0 >= 0){
      *(float4*)&al[wid][lane][0] =
        make_float4(p0.x*r4.x, p0.y*r4.y, p0.z*r4.z, p0.w*r4.w);
      sl[wid][lane] = s0;
    }
    if (s1 >= 0){
      *(float4*)&al[wid][lane+64][0] =
        make_float4(p1.x*r4.x, p1.y*r4.y, p1.z*r4.z, p1.w*r4.w);
      sl[wid][lane+64] = s1;
    }
  }
  __syncthreads();
  if (!valid) return;

  if (fast){
    int half = lane >> 5;
    int q    = lane & 31;   // feature quad: features q*4 .. q*4+3
    int hsel = q >> 3;      // owning head
    float4 acc = make_float4(0,0,0,0);
    int i = 0;
    for (; i + 4 <= cnt; i += 4){
      int e0 = i + half;
      int e1 = i + 2 + half;
      float a0 = al[wid][e0][hsel];
      float a1 = al[wid][e1][hsel];
      int   s0 = sl[wid][e0];
      int   s1 = sl[wid][e1];
      float4 h0 = ((const float4*)&Hin[(size_t)s0*128])[q];
      float4 h1 = ((const float4*)&Hin[(size_t)s1*128])[q];
      acc.x += a0*h0.x + a1*h1.x;
      acc.y += a0*h0.y + a1*h1.y;
      acc.z += a0*h0.z + a1*h1.z;
      acc.w += a0*h0.w + a1*h1.w;
    }
    for (; i < cnt; i += 2){
      int e = i + half;
      bool ev = e < cnt;
      int eidx = ev ? e : 0;
      float a  = ev ? al[wid][eidx][hsel] : 0.f;
      int src  = sl[wid][eidx];
      float4 hv = ((const float4*)&Hin[(size_t)src*128])[q];
      acc.x += a*hv.x; acc.y += a*hv.y; acc.z += a*hv.z; acc.w += a*hv.w;
    }
    acc.x += __shfl_xor(acc.x, 32);
    acc.y += __shfl_xor(acc.y, 32);
    acc.z += __shfl_xor(acc.z, 32);
    acc.w += __shfl_xor(acc.w, 32);
    if (CLS){
      float4 b  = *(const float4*)&bias[q*4];
      float4 wc = *(const float4*)&Wc[q*4];
      float v = (acc.x+b.x)*wc.x + (acc.y+b.y)*wc.y
              + (acc.z+b.z)*wc.z + (acc.w+b.w)*wc.w;
      v += __shfl_xor(v,1); v += __shfl_xor(v,2); v += __shfl_xor(v,4);
      v += __shfl_xor(v,8); v += __shfl_xor(v,16);
      if (lane == 0) Out[node] = 1.f/(1.f + __expf(-(v + bc[0])));
    } else {
      if (lane < 32) ((float4*)&Out[(size_t)node*128])[q] = acc;
    }
  } else {
    // ---- slow fallback (cnt > DCAP): online softmax + recompute ----
    float4 m = make_float4(-1e30f,-1e30f,-1e30f,-1e30f);
    float4 s = make_float4(0.f,0.f,0.f,0.f);
    for (int i = lane; i < cnt; i += 64){
      int src = csr_src[start + i];
      float4 a = *(const float4*)&As[(size_t)src*4];
      #define ONL(c) { float e = lrelu(a.c + ad4.c); float nm = fmaxf(m.c, e); \
                       s.c = s.c*__expf(m.c - nm) + __expf(e - nm); m.c = nm; }
      ONL(x) ONL(y) ONL(z) ONL(w)
      #undef ONL
    }
    #pragma unroll
    for (int off = 32; off; off >>= 1){
      #define CMB(c) { float mo = __shfl_xor(m.c, off); float so = __shfl_xor(s.c, off); \
                       float nm = fmaxf(m.c, mo); \
                       s.c = s.c*__expf(m.c - nm) + so*__expf(mo - nm); m.c = nm; }
      CMB(x) CMB(y) CMB(z) CMB(w)
      #undef CMB
    }
    bool hi = (lane & 32) != 0;
    float mA = hi ? m.y : m.x;
    float mB = hi ? m.w : m.z;
    float rA = 1.f / ((hi ? s.y : s.x) + 1e-16f);
    float rB = 1.f / ((hi ? s.w : s.z) + 1e-16f);
    float acc0 = 0.f, acc1 = 0.f;
    for (int i = 0; i < cnt; i++){
      int src = csr_src[start + i];
      float4 a = *(const float4*)&As[(size_t)src*4];
      float eA = hi ? lrelu(a.y + ad4.y) : lrelu(a.x + ad4.x);
      float eB = hi ? lrelu(a.w + ad4.w) : lrelu(a.z + ad4.z);
      float aA = __expf(eA - mA) * rA;
      float aB = __expf(eB - mB) * rB;
      const float* hrow = &Hin[(size_t)src*128];
      acc0 += aA * hrow[lane];
      acc1 += aB * hrow[64 + lane];
    }
    if (CLS){
      float v = (acc0 + bias[lane])*Wc[lane] + (acc1 + bias[64+lane])*Wc[64+lane];
      #pragma unroll
      for (int off = 32; off >= 1; off >>= 1) v += __shfl_xor(v, off);
      if (lane == 0) Out[node] = 1.f/(1.f + __expf(-(v + bc[0])));
    } else {
      Out[(size_t)node*128 + lane]      = acc0;
      Out[(size_t)node*128 + 64 + lane] = acc1;
    }
  }
}

// ---- launcher --------------------------------------------------------------

extern "C" void kernel_launch(void* const* d_in, const int* in_sizes, int n_in,
                              void* d_out, int out_size, void* d_ws, size_t ws_size,
                              hipStream_t stream)
{
  const float* x   = (const float*)d_in[0];
  const int*   ei  = (const int*)d_in[1];
  // d_in[2] = edge_attr (unused, edge_dim=None)
  const float* W1  = (const float*)d_in[3];
  const float* as1 = (const float*)d_in[4];
  const float* ad1 = (const float*)d_in[5];
  const float* b1  = (const float*)d_in[6];
  const float* W2  = (const float*)d_in[7];
  const float* as2 = (const float*)d_in[8];
  const float* ad2 = (const float*)d_in[9];
  const float* b2  = (const float*)d_in[10];
  const float* Wc  = (const float*)d_in[11];
  const float* bc  = (const float*)d_in[12];
  float* y = (float*)d_out;

  char* w = (char*)d_ws;
  auto take = [&](size_t bytes)->char*{
    char* p = w; w += (bytes + 255) & ~(size_t)255; return p;
  };
  float* A      = (float*)take((size_t)NN*128*4);  // h (current layer)
  float* B      = (float*)take((size_t)NN*128*4);  // layer-1 aggregated output
  float* As     = (float*)take((size_t)NN*4*4);
  float* Ad     = (float*)take((size_t)NN*4*4);
  int*   count  = (int*)  take((size_t)NN*4);
  int*   offs   = (int*)  take((size_t)NN*4);
  int*   cursor = (int*)  take((size_t)NN*4);
  int*   btot   = (int*)  take(64*4);
  int*   csr    = (int*)  take((size_t)ET*4);      // src per CSR slot (sorted by dst)
  (void)ws_size; (void)in_sizes; (void)n_in; (void)out_size;

  const int EB  = (ET + 255)/256;
  const int NB4 = (NN + 3)/4;

  // CSR build (graph identical for both layers)
  hipMemsetAsync(count, 0, (size_t)NN*4, stream);
  k_hist   <<<EB, 256, 0, stream>>>(ei, count);
  k_scan1  <<<49, 1024, 0, stream>>>(count, offs, btot, NN);
  k_scan2  <<<1, 64, 0, stream>>>(btot, 49);
  k_scan3  <<<49, 1024, 0, stream>>>(offs, count, btot, cursor, NN);
  k_scatter<<<EB, 256, 0, stream>>>(ei, cursor, csr);

  // ---- layer 1 ----
  k_gemm_att<<<512, 256, 0, stream>>>(x, nullptr, W1, as1, ad1, A, As, Ad);
  k_aggr2<0><<<NB4, 256, 0, stream>>>(csr, offs, count, A, As, Ad, B,
                                      nullptr, nullptr, nullptr);

  // ---- layer 2 ---- (input bias b1 folded as b1@W2; classifier fused)
  k_gemm_att<<<512, 256, 0, stream>>>(B, b1, W2, as2, ad2, A, As, Ad);
  k_aggr2<1><<<NB4, 256, 0, stream>>>(csr, offs, count, A, As, Ad, y,
                                      b2, Wc, bc);
}

// Round 9
// 397.205 us; speedup vs baseline: 3.0898x; 1.0241x over previous
//
#include <hip/hip_runtime.h>
#include <stdint.h>

// GAT (2-layer) + sigmoid classifier for MI355X.
// N=50000 nodes, E=800000 edges (+N self loops), 128 features, 4 heads x 32.
//
// R8: aggregation = half-wave (32 lanes) per node, 8 nodes/block, no
// __syncthreads, 4-edge unrolled gather (4 x 512B loads in flight).

#define NN 50000
#define NE 800000
#define ET 850000   // NE + NN self-loops
#define DCAP 128    // LDS alpha slots per node (Poisson(17) degrees; fallback beyond)

__device__ __forceinline__ float lrelu(float v){ return v > 0.f ? v : 0.2f*v; }
__device__ __forceinline__ float comp4(float4 v, int i){
  float r = v.x;
  r = (i == 1) ? v.y : r;
  r = (i == 2) ? v.z : r;
  r = (i == 3) ? v.w : r;
  return r;
}

// ---- CSR build -------------------------------------------------------------

__global__ void k_hist(const int* __restrict__ ei, int* __restrict__ count){
  int e = blockIdx.x*256 + threadIdx.x;
  if (e >= ET) return;
  int dst = (e < NE) ? ei[NE + e] : (e - NE);
  atomicAdd(&count[dst], 1);
}

__global__ void k_scan1(const int* __restrict__ count, int* __restrict__ incl,
                        int* __restrict__ btot, int n){
  __shared__ int sm[1024];
  int i = blockIdx.x*1024 + threadIdx.x;
  int v = (i < n) ? count[i] : 0;
  sm[threadIdx.x] = v;
  __syncthreads();
  for (int off = 1; off < 1024; off <<= 1){
    int t = (threadIdx.x >= off) ? sm[threadIdx.x - off] : 0;
    __syncthreads();
    sm[threadIdx.x] += t;
    __syncthreads();
  }
  if (i < n) incl[i] = sm[threadIdx.x];
  if (threadIdx.x == 1023) btot[blockIdx.x] = sm[1023];
}

__global__ void k_scan2(int* btot, int nb){  // single-wave exclusive scan
  int t = threadIdx.x;
  int orig = (t < nb) ? btot[t] : 0;
  int v = orig;
  for (int off = 1; off < 64; off <<= 1){
    int u = __shfl_up(v, off);
    if (t >= off) v += u;
  }
  if (t < nb) btot[t] = v - orig;
}

__global__ void k_scan3(int* __restrict__ offs_incl, const int* __restrict__ count,
                        const int* __restrict__ btot, int* __restrict__ cursor, int n){
  int i = blockIdx.x*1024 + threadIdx.x;
  if (i >= n) return;
  int excl = offs_incl[i] - count[i] + btot[blockIdx.x];
  offs_incl[i] = excl;   // in-place: incl -> excl
  cursor[i] = excl;
}

__global__ void k_scatter(const int* __restrict__ ei, int* __restrict__ cursor,
                          int* __restrict__ csr_src){
  int e = blockIdx.x*256 + threadIdx.x;
  if (e >= ET) return;
  int src, dst;
  if (e < NE){ src = ei[e]; dst = ei[NE + e]; } else { src = dst = e - NE; }
  int pos = atomicAdd(&cursor[dst], 1);
  csr_src[pos] = src;
}

// ---- GEMM (X @ W) fused with attention dot products ------------------------
// Block tile 32 rows x 128 cols; thread = 4 rows x 4 contiguous cols.
// LDS: W 64 KB + X tile 16 KB = 80 KB -> 2 blocks/CU (8 waves/CU).
// Layer-2 input bias b1 folded as (b1 @ W2) into the accumulator init.

__launch_bounds__(256, 2)
__global__ void k_gemm_att(const float* __restrict__ X, const float* __restrict__ bias_in,
                           const float* __restrict__ W,
                           const float* __restrict__ att_s, const float* __restrict__ att_d,
                           float* __restrict__ Hout, float* __restrict__ As, float* __restrict__ Ad)
{
  __shared__ float Ws[128*128];   // 64 KB
  __shared__ float xs[32*128];    // 16 KB
  int tid  = threadIdx.x;
  int rowq = tid >> 5;            // 0..7  (4 rows each)
  int colq = tid & 31;            // 0..31 (4 cols each)
  int c0   = colq*4;

  for (int i = tid*4; i < 128*128; i += 256*4)
    *(float4*)&Ws[i] = *(const float4*)&W[i];
  __syncthreads();

  float4 bW = make_float4(0.f,0.f,0.f,0.f);
  if (bias_in){
    for (int k = 0; k < 128; k++){
      float b = bias_in[k];
      float4 wv = *(float4*)&Ws[k*128 + c0];
      bW.x += b*wv.x; bW.y += b*wv.y; bW.z += b*wv.z; bW.w += b*wv.w;
    }
  }
  float4 atts = *(const float4*)&att_s[c0];
  float4 attd = *(const float4*)&att_d[c0];

  const int ntiles = (NN + 31)/32;
  for (int t = blockIdx.x; t < ntiles; t += gridDim.x){
    int base = t*32;
    #pragma unroll
    for (int q = 0; q < 4; q++){
      int f = q*1024 + tid*4;          // flat float index into 32x128 tile
      int r = base + (f >> 7);
      if (r >= NN) r = NN-1;           // clamp tail (stores guarded below)
      *(float4*)&xs[f] = *(const float4*)&X[(size_t)r*128 + (f & 127)];
    }
    __syncthreads();

    float4 acc[4];
    #pragma unroll
    for (int i = 0; i < 4; i++) acc[i] = bW;

    for (int k = 0; k < 128; k += 4){
      float4 w0 = *(float4*)&Ws[(k+0)*128 + c0];
      float4 w1 = *(float4*)&Ws[(k+1)*128 + c0];
      float4 w2 = *(float4*)&Ws[(k+2)*128 + c0];
      float4 w3 = *(float4*)&Ws[(k+3)*128 + c0];
      #pragma unroll
      for (int i = 0; i < 4; i++){
        float4 xv = *(float4*)&xs[(rowq*4+i)*128 + k];
        acc[i].x += xv.x*w0.x + xv.y*w1.x + xv.z*w2.x + xv.w*w3.x;
        acc[i].y += xv.x*w0.y + xv.y*w1.y + xv.z*w2.y + xv.w*w3.y;
        acc[i].z += xv.x*w0.z + xv.y*w1.z + xv.z*w2.z + xv.w*w3.z;
        acc[i].w += xv.x*w0.w + xv.y*w1.w + xv.z*w2.w + xv.w*w3.w;
      }
    }

    #pragma unroll
    for (int i = 0; i < 4; i++){
      int row = base + rowq*4 + i;
      bool ok = row < NN;
      if (ok) *(float4*)&Hout[(size_t)row*128 + c0] = acc[i];
      // attention dots: reduce over the 8 threads (32 dims) of this head
      float ps = acc[i].x*atts.x + acc[i].y*atts.y + acc[i].z*atts.z + acc[i].w*atts.w;
      float pd = acc[i].x*attd.x + acc[i].y*attd.y + acc[i].z*attd.z + acc[i].w*attd.w;
      ps += __shfl_xor(ps,1); ps += __shfl_xor(ps,2); ps += __shfl_xor(ps,4);
      pd += __shfl_xor(pd,1); pd += __shfl_xor(pd,2); pd += __shfl_xor(pd,4);
      if (ok && (colq & 7) == 0){
        As[row*4 + (colq>>3)] = ps;
        Ad[row*4 + (colq>>3)] = pd;
      }
    }
    __syncthreads();
  }
}

// ---- fused softmax + aggregation (+ optional classifier epilogue) ----------
// HALF-WAVE (32 lanes) per node; 8 nodes per 256-thread block; NO barriers
// (each half-wave produces and consumes its own LDS region).
// Phase 1: lane owns edge slots {l, l+32, l+64, l+96}; exact 2-pass softmax
//          with width-32 butterflies; alpha -> al[hw][edge][head].
// Phase 2: lane owns feature quad q=l (features 4q..4q+3); 4 edges/iter with
//          4 independent 512B row loads in flight per half-wave.
// CLS=1: sigmoid((acc + bias) . Wc + bc) epilogue instead of storing the row.

template<int CLS>
__launch_bounds__(256)
__global__ void k_aggr3(const int* __restrict__ csr_src, const int* __restrict__ offs,
                        const int* __restrict__ count, const float* __restrict__ Hin,
                        const float* __restrict__ As, const float* __restrict__ Ad,
                        float* __restrict__ Out,
                        const float* __restrict__ bias, const float* __restrict__ Wc,
                        const float* __restrict__ bc)
{
  __shared__ float al[8][DCAP][4];  // 16 KB
  __shared__ int   sl[8][DCAP];     //  4 KB
  int tid = threadIdx.x;
  int hw  = tid >> 5;               // half-wave 0..7 = node slot
  int l   = tid & 31;               // lane within half
  int node = blockIdx.x*8 + hw;
  if (node >= NN) return;
  int start = offs[node];
  int cnt   = count[node];
  float4 ad4 = *(const float4*)&Ad[(size_t)node*4];
  int q    = l;                     // feature quad
  int hsel = q >> 3;                // owning head
  const float4* Hq = (const float4*)Hin;   // row stride = 32 float4

  if (cnt <= DCAP){
    // ---- phase 1: exact softmax over up to 128 edges, 4 slots per lane ----
    float4 e0, e1, e2, e3;
    int s0 = -1, s1 = -1, s2 = -1, s3 = -1;
    float4 m = make_float4(-1e30f,-1e30f,-1e30f,-1e30f);
    #define SLOT(K, sK, eK)                                        \
      if (l + K*32 < cnt){                                         \
        sK = csr_src[start + l + K*32];                            \
        float4 a = *(const float4*)&As[(size_t)sK*4];              \
        eK.x = lrelu(a.x+ad4.x); eK.y = lrelu(a.y+ad4.y);          \
        eK.z = lrelu(a.z+ad4.z); eK.w = lrelu(a.w+ad4.w);          \
        m.x = fmaxf(m.x, eK.x); m.y = fmaxf(m.y, eK.y);            \
        m.z = fmaxf(m.z, eK.z); m.w = fmaxf(m.w, eK.w);            \
      }
    SLOT(0, s0, e0) SLOT(1, s1, e1) SLOT(2, s2, e2) SLOT(3, s3, e3)
    #undef SLOT
    #pragma unroll
    for (int off = 16; off; off >>= 1){
      m.x = fmaxf(m.x, __shfl_xor(m.x, off));
      m.y = fmaxf(m.y, __shfl_xor(m.y, off));
      m.z = fmaxf(m.z, __shfl_xor(m.z, off));
      m.w = fmaxf(m.w, __shfl_xor(m.w, off));
    }
    float4 sum = make_float4(0.f,0.f,0.f,0.f);
    float4 p0, p1, p2, p3;
    #define EXPS(sK, eK, pK)                                       \
      if (sK >= 0){                                                \
        pK.x = __expf(eK.x - m.x); pK.y = __expf(eK.y - m.y);      \
        pK.z = __expf(eK.z - m.z); pK.w = __expf(eK.w - m.w);      \
        sum.x += pK.x; sum.y += pK.y; sum.z += pK.z; sum.w += pK.w;\
      }
    EXPS(s0, e0, p0) EXPS(s1, e1, p1) EXPS(s2, e2, p2) EXPS(s3, e3, p3)
    #undef EXPS
    #pragma unroll
    for (int off = 16; off; off >>= 1){
      sum.x += __shfl_xor(sum.x, off);
      sum.y += __shfl_xor(sum.y, off);
      sum.z += __shfl_xor(sum.z, off);
      sum.w += __shfl_xor(sum.w, off);
    }
    float4 r4 = make_float4(1.f/(sum.x+1e-16f), 1.f/(sum.y+1e-16f),
                            1.f/(sum.z+1e-16f), 1.f/(sum.w+1e-16f));
    #define STORE(K, sK, pK)                                       \
      if (sK >= 0){                                                \
        *(float4*)&al[hw][l + K*32][0] =                           \
          make_float4(pK.x*r4.x, pK.y*r4.y, pK.z*r4.z, pK.w*r4.w); \
        sl[hw][l + K*32] = sK;                                     \
      }
    STORE(0, s0, p0) STORE(1, s1, p1) STORE(2, s2, p2) STORE(3, s3, p3)
    #undef STORE
    // same half-wave reads its own writes; compiler inserts lgkmcnt waits

    // ---- phase 2: 4 edges/iter, 4 row loads in flight ----
    float4 acc = make_float4(0.f,0.f,0.f,0.f);
    int i = 0;
    for (; i + 4 <= cnt; i += 4){
      int   t0 = sl[hw][i],   t1 = sl[hw][i+1];
      int   t2 = sl[hw][i+2], t3 = sl[hw][i+3];
      float a0 = al[hw][i][hsel],   a1 = al[hw][i+1][hsel];
      float a2 = al[hw][i+2][hsel], a3 = al[hw][i+3][hsel];
      float4 h0 = Hq[(size_t)t0*32 + q];
      float4 h1 = Hq[(size_t)t1*32 + q];
      float4 h2 = Hq[(size_t)t2*32 + q];
      float4 h3 = Hq[(size_t)t3*32 + q];
      acc.x += a0*h0.x + a1*h1.x + a2*h2.x + a3*h3.x;
      acc.y += a0*h0.y + a1*h1.y + a2*h2.y + a3*h3.y;
      acc.z += a0*h0.z + a1*h1.z + a2*h2.z + a3*h3.z;
      acc.w += a0*h0.w + a1*h1.w + a2*h2.w + a3*h3.w;
    }
    for (; i < cnt; i++){
      int   t0 = sl[hw][i];
      float a0 = al[hw][i][hsel];
      float4 h0 = Hq[(size_t)t0*32 + q];
      acc.x += a0*h0.x; acc.y += a0*h0.y; acc.z += a0*h0.z; acc.w += a0*h0.w;
    }
    if (CLS){
      float4 b  = *(const float4*)&bias[q*4];
      float4 wc = *(const float4*)&Wc[q*4];
      float v = (acc.x+b.x)*wc.x + (acc.y+b.y)*wc.y
              + (acc.z+b.z)*wc.z + (acc.w+b.w)*wc.w;
      v += __shfl_xor(v,1); v += __shfl_xor(v,2); v += __shfl_xor(v,4);
      v += __shfl_xor(v,8); v += __shfl_xor(v,16);
      if (l == 0) Out[node] = 1.f/(1.f + __expf(-(v + bc[0])));
    } else {
      ((float4*)&Out[(size_t)node*128])[q] = acc;
    }
  } else {
    // ---- slow fallback (cnt > DCAP): online softmax, 32-lane ----
    float4 m = make_float4(-1e30f,-1e30f,-1e30f,-1e30f);
    float4 s = make_float4(0.f,0.f,0.f,0.f);
    for (int i = l; i < cnt; i += 32){
      int src = csr_src[start + i];
      float4 a = *(const float4*)&As[(size_t)src*4];
      #define ONL(c) { float e = lrelu(a.c + ad4.c); float nm = fmaxf(m.c, e); \
                       s.c = s.c*__expf(m.c - nm) + __expf(e - nm); m.c = nm; }
      ONL(x) ONL(y) ONL(z) ONL(w)
      #undef ONL
    }
    #pragma unroll
    for (int off = 16; off; off >>= 1){
      #define CMB(c) { float mo = __shfl_xor(m.c, off); float so = __shfl_xor(s.c, off); \
                       float nm = fmaxf(m.c, mo); \
                       s.c = s.c*__expf(m.c - nm) + so*__expf(mo - nm); m.c = nm; }
      CMB(x) CMB(y) CMB(z) CMB(w)
      #undef CMB
    }
    float mh  = comp4(m, hsel);
    float rh  = 1.f / (comp4(s, hsel) + 1e-16f);
    float adh = comp4(ad4, hsel);
    float4 acc = make_float4(0.f,0.f,0.f,0.f);
    for (int i = 0; i < cnt; i++){
      int src = csr_src[start + i];
      float a = As[(size_t)src*4 + hsel];
      float alpha = __expf(lrelu(a + adh) - mh) * rh;
      float4 hv = Hq[(size_t)src*32 + q];
      acc.x += alpha*hv.x; acc.y += alpha*hv.y;
      acc.z += alpha*hv.z; acc.w += alpha*hv.w;
    }
    if (CLS){
      float4 b  = *(const float4*)&bias[q*4];
      float4 wc = *(const float4*)&Wc[q*4];
      float v = (acc.x+b.x)*wc.x + (acc.y+b.y)*wc.y
              + (acc.z+b.z)*wc.z + (acc.w+b.w)*wc.w;
      v += __shfl_xor(v,1); v += __shfl_xor(v,2); v += __shfl_xor(v,4);
      v += __shfl_xor(v,8); v += __shfl_xor(v,16);
      if (l == 0) Out[node] = 1.f/(1.f + __expf(-(v + bc[0])));
    } else {
      ((float4*)&Out[(size_t)node*128])[q] = acc;
    }
  }
}

// ---- launcher --------------------------------------------------------------

extern "C" void kernel_launch(void* const* d_in, const int* in_sizes, int n_in,
                              void* d_out, int out_size, void* d_ws, size_t ws_size,
                              hipStream_t stream)
{
  const float* x   = (const float*)d_in[0];
  const int*   ei  = (const int*)d_in[1];
  // d_in[2] = edge_attr (unused, edge_dim=None)
  const float* W1  = (const float*)d_in[3];
  const float* as1 = (const float*)d_in[4];
  const float* ad1 = (const float*)d_in[5];
  const float* b1  = (const float*)d_in[6];
  const float* W2  = (const float*)d_in[7];
  const float* as2 = (const float*)d_in[8];
  const float* ad2 = (const float*)d_in[9];
  const float* b2  = (const float*)d_in[10];
  const float* Wc  = (const float*)d_in[11];
  const float* bc  = (const float*)d_in[12];
  float* y = (float*)d_out;

  char* w = (char*)d_ws;
  auto take = [&](size_t bytes)->char*{
    char* p = w; w += (bytes + 255) & ~(size_t)255; return p;
  };
  float* A      = (float*)take((size_t)NN*128*4);  // h (current layer)
  float* B      = (float*)take((size_t)NN*128*4);  // layer-1 aggregated output
  float* As     = (float*)take((size_t)NN*4*4);
  float* Ad     = (float*)take((size_t)NN*4*4);
  int*   count  = (int*)  take((size_t)NN*4);
  int*   offs   = (int*)  take((size_t)NN*4);
  int*   cursor = (int*)  take((size_t)NN*4);
  int*   btot   = (int*)  take(64*4);
  int*   csr    = (int*)  take((size_t)ET*4);      // src per CSR slot (sorted by dst)
  (void)ws_size; (void)in_sizes; (void)n_in; (void)out_size;

  const int EB  = (ET + 255)/256;
  const int NB8 = (NN + 7)/8;

  // CSR build (graph identical for both layers)
  hipMemsetAsync(count, 0, (size_t)NN*4, stream);
  k_hist   <<<EB, 256, 0, stream>>>(ei, count);
  k_scan1  <<<49, 1024, 0, stream>>>(count, offs, btot, NN);
  k_scan2  <<<1, 64, 0, stream>>>(btot, 49);
  k_scan3  <<<49, 1024, 0, stream>>>(offs, count, btot, cursor, NN);
  k_scatter<<<EB, 256, 0, stream>>>(ei, cursor, csr);

  // ---- layer 1 ----
  k_gemm_att<<<512, 256, 0, stream>>>(x, nullptr, W1, as1, ad1, A, As, Ad);
  k_aggr3<0><<<NB8, 256, 0, stream>>>(csr, offs, count, A, As, Ad, B,
                                      nullptr, nullptr, nullptr);

  // ---- layer 2 ---- (input bias b1 folded as b1@W2; classifier fused)
  k_gemm_att<<<512, 256, 0, stream>>>(B, b1, W2, as2, ad2, A, As, Ad);
  k_aggr3<1><<<NB8, 256, 0, stream>>>(csr, offs, count, A, As, Ad, y,
                                      b2, Wc, bc);
}